// Round 5
// baseline (168.934 us; speedup 1.0000x reference)
//
#include <hip/hip_runtime.h>
#include <hip/hip_bf16.h>
#include <math.h>

typedef __bf16 bf16;
typedef bf16 bf16x8 __attribute__((ext_vector_type(8)));
typedef bf16 bf16x4 __attribute__((ext_vector_type(4)));
typedef float f32x4 __attribute__((ext_vector_type(4)));

#define N_NODES 8192
#define DIN 256
#define DOUT 256
#define KCAT 512
#define EPSF 1e-8f
#define KSPLIT 4
#define KBLK 2048          // K per k2 block
#define BM 128
#define BK 32
#define NT (KBLK / BK)     // 64 tiles
#define STAGE 24576        // A 8 KB + B 16 KB per stage
#define BBASE 8192         // B region offset within stage

__device__ __forceinline__ f32x4 mfma16(bf16x8 a, bf16x8 b, f32x4 c) {
    return __builtin_amdgcn_mfma_f32_16x16x32_bf16(a, b, c, 0, 0, 0);
}

#define WAITVM(N) asm volatile("s_waitcnt vmcnt(" #N ")" ::: "memory")
#define WAITLGKM  asm volatile("s_waitcnt lgkmcnt(0)" ::: "memory")
#define BAR       __builtin_amdgcn_s_barrier()

// ---------------- K0: W_w [256x256] -> WwT[n][k] bf16 ; W_fc [512x256] -> WfcT[n][k] bf16
__global__ __launch_bounds__(256) void k0_prep(const float* __restrict__ Ww,
                                               const float* __restrict__ Wfc,
                                               bf16* __restrict__ WwT,
                                               bf16* __restrict__ WfcT) {
    int tid = blockIdx.x * 256 + threadIdx.x;
    if (tid < 256 * 256) {
        int n = tid >> 8, k = tid & 255;
        WwT[n * 256 + k] = (bf16)Ww[k * 256 + n];
    }
    if (tid < 256 * 512) {
        int n = tid >> 9, k = tid & 511;
        WfcT[n * 512 + k] = (bf16)Wfc[k * 256 + n];
    }
}

// ---------------- K1: hT[col][m] = bf16(relu(X @ W_w + b_w))
__global__ __launch_bounds__(128) void k1_h(const float* __restrict__ X,
                                            const bf16* __restrict__ WwT,
                                            const float* __restrict__ bw,
                                            bf16* __restrict__ hT) {
    const int lane = threadIdx.x & 63;
    const int wid  = threadIdx.x >> 6;   // 0..1
    const int m0   = blockIdx.x * 16;
    const int lrow = lane & 15;
    const int lk8  = (lane >> 4) * 8;

    f32x4 acc[8];
#pragma unroll
    for (int i = 0; i < 8; ++i) acc[i] = {0.f, 0.f, 0.f, 0.f};

#pragma unroll
    for (int ks = 0; ks < DIN; ks += 32) {
        const float* xp = X + (size_t)(m0 + lrow) * DIN + ks + lk8;
        f32x4 x0 = *reinterpret_cast<const f32x4*>(xp);
        f32x4 x1 = *reinterpret_cast<const f32x4*>(xp + 4);
        bf16x8 a;
#pragma unroll
        for (int j = 0; j < 4; ++j) { a[j] = (bf16)x0[j]; a[4 + j] = (bf16)x1[j]; }
#pragma unroll
        for (int nb = 0; nb < 8; ++nb) {
            int col = wid * 128 + nb * 16 + lrow;
            bf16x8 b = *reinterpret_cast<const bf16x8*>(WwT + (size_t)col * DIN + ks + lk8);
            acc[nb] = mfma16(a, b, acc[nb]);
        }
    }
    const int mrow = m0 + (lane >> 4) * 4;
#pragma unroll
    for (int nb = 0; nb < 8; ++nb) {
        int col = wid * 128 + nb * 16 + lrow;
        float bias = bw[col];
        bf16x4 hv;
#pragma unroll
        for (int j = 0; j < 4; ++j) {
            float v = acc[nb][j] + bias;
            hv[j] = (bf16)(v > 0.f ? v : 0.f);
        }
        *reinterpret_cast<bf16x4*>(hT + (size_t)col * N_NODES + mrow) = hv;
    }
}

// ---------------- K2: part[ks] = A[m0:m0+128, kbase:+2048] @ h ; rsG[ks] = rowsum partial
// grid 256 = 64 M-blocks x 4 K-splits (1 block/CU), 512 thr = 8 waves (2x4 of 64x64).
// 4-stage LDS pipeline (98 KB): B-DMA issued 3 tiles ahead, A-regs 3 sets deep.
// Counted vmcnt only: steady WAITVM(10) retires exactly through B(t+1).
// A: 2x f32x4 coalesced -> cvt bf16 -> swizzled ds_write_b128 (8 KB/tile).
// B: 2x global_load_lds dwordx4, source-pre-swizzled, linear LDS dest (16 KB/tile).
// Swizzle (64B row pitch): phys_seg = seg ^ ((row>>1)&3) on both write and read.
__global__ __launch_bounds__(512, 2) void k2_pool(const float* __restrict__ A,
                                                  const bf16* __restrict__ hT,
                                                  float* __restrict__ part,
                                                  float* __restrict__ rsG) {
    __shared__ __align__(16) unsigned char lds[4][STAGE];
    __shared__ float rsp[4][BM];
    const int t    = threadIdx.x;
    const int lane = t & 63;
    const int wid  = t >> 6;        // 0..7
    const int wr   = wid >> 2;      // 0..1  (64-row half)
    const int wn   = wid & 3;       // 0..3  (64-col quarter)
    const int lrow = lane & 15;
    const int lk4  = lane >> 4;     // 0..3 (16B k-seg)
    const int mblk = blockIdx.x & 63;
    const int ks   = blockIdx.x >> 6;
    const int m0   = mblk * BM;
    const int kbase = ks * KBLK;

    f32x4 acc[4][4];
    f32x4 sums[4];
#pragma unroll
    for (int i = 0; i < 4; ++i) {
        sums[i] = {0.f, 0.f, 0.f, 0.f};
#pragma unroll
        for (int j = 0; j < 4; ++j) acc[i][j] = {0.f, 0.f, 0.f, 0.f};
    }
    bf16x8 bOne;
#pragma unroll
    for (int j = 0; j < 8; ++j) bOne[j] = (bf16)1.0f;

    // ---- A staging: thread t -> row t>>2, seg (t&3) (8 floats -> 16B bf16)
    const int arow = t >> 2;
    const int aseg = t & 3;
    const float* aSrc = A + (size_t)(m0 + arow) * N_NODES + kbase + aseg * 8;
    const int awb = arow * 64 + ((aseg ^ ((arow >> 1) & 3)) << 4);

    // ---- B DMA (2 rounds): idx=r*512+t -> col=idx>>2, phys seg=idx&3,
    //      global seg gs = (idx&3) ^ ((col>>1)&3); LDS dest linear.
    const bf16* bsrc[2];
    int bdst[2];
#pragma unroll
    for (int r = 0; r < 2; ++r) {
        int idx = r * 512 + t;
        int col = idx >> 2;
        int gs  = (idx & 3) ^ ((col >> 1) & 3);
        bsrc[r] = hT + (size_t)col * N_NODES + kbase + gs * 8;
        bdst[r] = BBASE + r * 8192 + wid * 1024;   // + lane*16 applied by HW
    }

    // ---- fragment read byte offsets
    int aOff[4], bOff[4];
#pragma unroll
    for (int mf = 0; mf < 4; ++mf) {
        int row = wr * 64 + mf * 16 + lrow;
        aOff[mf] = row * 64 + ((lk4 ^ ((row >> 1) & 3)) << 4);
    }
#pragma unroll
    for (int nf = 0; nf < 4; ++nf) {
        int col = wn * 64 + nf * 16 + lrow;
        bOff[nf] = BBASE + col * 64 + ((lk4 ^ ((col >> 1) & 3)) << 4);
    }

    f32x4 rlo[3], rhi[3];   // 3 A-reg sets

#define ALOAD(set, tile) do {                                                 \
        const float* p_ = aSrc + (size_t)(tile) * BK;                         \
        rlo[set] = *reinterpret_cast<const f32x4*>(p_);                       \
        rhi[set] = *reinterpret_cast<const f32x4*>(p_ + 4);                   \
    } while (0)

#define CVTWRITE(set, bufidx) do {                                            \
        bf16x8 w_;                                                            \
        _Pragma("unroll")                                                     \
        for (int j = 0; j < 4; ++j) {                                         \
            w_[j] = (bf16)rlo[set][j]; w_[4 + j] = (bf16)rhi[set][j];         \
        }                                                                     \
        *reinterpret_cast<bf16x8*>(&lds[bufidx][awb]) = w_;                   \
    } while (0)

#define BDMA(tile, bufidx) do {                                               \
        _Pragma("unroll")                                                     \
        for (int r_ = 0; r_ < 2; ++r_) {                                      \
            __builtin_amdgcn_global_load_lds(                                 \
                (const __attribute__((address_space(1))) void*)(bsrc[r_] + (size_t)(tile) * BK), \
                (__attribute__((address_space(3))) void*)&lds[bufidx][bdst[r_]], \
                16, 0, 0);                                                    \
        }                                                                     \
    } while (0)

#define COMPUTE(bufidx, tile) do {                                            \
        bf16x8 af_[4], bf_[4];                                                \
        _Pragma("unroll")                                                     \
        for (int f = 0; f < 4; ++f)                                           \
            af_[f] = *reinterpret_cast<const bf16x8*>(&lds[bufidx][aOff[f]]); \
        _Pragma("unroll")                                                     \
        for (int f = 0; f < 4; ++f)                                           \
            bf_[f] = *reinterpret_cast<const bf16x8*>(&lds[bufidx][bOff[f]]); \
        _Pragma("unroll")                                                     \
        for (int mf = 0; mf < 4; ++mf)                                        \
            _Pragma("unroll")                                                 \
            for (int nf = 0; nf < 4; ++nf)                                    \
                acc[mf][nf] = mfma16(af_[mf], bf_[nf], acc[mf][nf]);          \
        if (wn == ((tile) & 3)) {                                             \
            _Pragma("unroll")                                                 \
            for (int mf = 0; mf < 4; ++mf)                                    \
                sums[mf] = mfma16(af_[mf], bOne, sums[mf]);                   \
        }                                                                     \
    } while (0)

    // ---------------- prologue (leaves steady entry queue [A1,B1,A2,B2,A3] = 10)
    ALOAD(0, 0); BDMA(0, 0);
    ALOAD(1, 1); BDMA(1, 1);
    ALOAD(2, 2); BDMA(2, 2);
    CVTWRITE(0, 0);              // compiler-inserted vmcnt for A0 regs
    ALOAD(0, 3);
    WAITVM(10);                  // retire through B(0)
    WAITLGKM;
    BAR;                         // tile 0 ready

    // ---------------- main loop: t = 0 .. NT-4
    for (int tt = 0; tt < NT - 3; ++tt) {
        CVTWRITE((tt + 1) % 3, (tt + 1) & 3);   // A(tt+1) regs -> LDS
        COMPUTE(tt & 3, tt);
        BDMA(tt + 3, (tt + 3) & 3);             // B 3 tiles ahead
        ALOAD((tt + 1) % 3, (tt + 4 < NT) ? (tt + 4) : 0);  // A 3 sets deep (clamped)
        WAITVM(10);              // retire through B(tt+1)
        WAITLGKM;
        BAR;                     // tile tt+1 ready; buf (tt+3)&3 reuse is 3 barriers past
    }
    // ---------------- epilogue: tiles NT-3, NT-2, NT-1
    CVTWRITE((NT - 2) % 3, (NT - 2) & 3);
    COMPUTE((NT - 3) & 3, NT - 3);
    WAITVM(6);                   // retire through B(NT-2)
    WAITLGKM;
    BAR;
    CVTWRITE((NT - 1) % 3, (NT - 1) & 3);
    COMPUTE((NT - 2) & 3, NT - 2);
    WAITVM(2);                   // retire through B(NT-1)
    WAITLGKM;
    BAR;
    COMPUTE((NT - 1) & 3, NT - 1);

    // ---------------- rowsum reduce across wn quarters
    __syncthreads();
    if (lrow == 0) {
#pragma unroll
        for (int mf = 0; mf < 4; ++mf)
#pragma unroll
            for (int j = 0; j < 4; ++j)
                rsp[wn][wr * 64 + mf * 16 + lk4 * 4 + j] = sums[mf][j];
    }
    __syncthreads();
    if (t < BM)
        rsG[(size_t)ks * N_NODES + m0 + t] = rsp[0][t] + rsp[1][t] + rsp[2][t] + rsp[3][t];

    // ---------------- store f32 partial tile
    float* pp = part + ((size_t)ks * N_NODES + m0) * DOUT;
#pragma unroll
    for (int mf = 0; mf < 4; ++mf)
#pragma unroll
        for (int nf = 0; nf < 4; ++nf) {
            int col = wn * 64 + nf * 16 + lrow;
#pragma unroll
            for (int j = 0; j < 4; ++j) {
                int row = wr * 64 + mf * 16 + lk4 * 4 + j;
                pp[(size_t)row * DOUT + col] = acc[mf][nf][j];
            }
        }
#undef ALOAD
#undef CVTWRITE
#undef BDMA
#undef COMPUTE
}

// ---------------- K3: out = relu([X || pooled] @ W_fc + b_fc) + eps  (pooled formed
// on the fly from part/rsG — k2b merged in), + per-block sumsq partial
__global__ __launch_bounds__(128) void k3_out(const float* __restrict__ X,
                                              const float* __restrict__ part,
                                              const float* __restrict__ rsG,
                                              const bf16* __restrict__ WfcT,
                                              const float* __restrict__ bfc,
                                              float* __restrict__ out,
                                              float* __restrict__ partials) {
    const int lane = threadIdx.x & 63;
    const int wid  = threadIdx.x >> 6;
    const int m0   = blockIdx.x * 16;
    const int lrow = lane & 15;
    const int lk8  = (lane >> 4) * 8;

    f32x4 acc[8];
#pragma unroll
    for (int i = 0; i < 8; ++i) acc[i] = {0.f, 0.f, 0.f, 0.f};

    // per-lane row scale 1/(rowsum+eps) for row m0+lrow
    float rs = EPSF;
#pragma unroll
    for (int sp = 0; sp < KSPLIT; ++sp) rs += rsG[(size_t)sp * N_NODES + m0 + lrow];
    const float inv = 1.f / rs;

    // k in [0,256): A-operand from X (fp32 -> bf16)
#pragma unroll
    for (int ksx = 0; ksx < 256; ksx += 32) {
        const float* xp = X + (size_t)(m0 + lrow) * DIN + ksx + lk8;
        f32x4 x0 = *reinterpret_cast<const f32x4*>(xp);
        f32x4 x1 = *reinterpret_cast<const f32x4*>(xp + 4);
        bf16x8 a;
#pragma unroll
        for (int j = 0; j < 4; ++j) { a[j] = (bf16)x0[j]; a[4 + j] = (bf16)x1[j]; }
#pragma unroll
        for (int nb = 0; nb < 8; ++nb) {
            int col = wid * 128 + nb * 16 + lrow;
            bf16x8 b = *reinterpret_cast<const bf16x8*>(WfcT + (size_t)col * KCAT + ksx + lk8);
            acc[nb] = mfma16(a, b, acc[nb]);
        }
    }
    // k in [256,512): A-operand = pooled, formed from sum of part splits * inv
#pragma unroll
    for (int ksx = 256; ksx < 512; ksx += 32) {
        f32x4 s0 = {0.f, 0.f, 0.f, 0.f}, s1 = {0.f, 0.f, 0.f, 0.f};
#pragma unroll
        for (int sp = 0; sp < KSPLIT; ++sp) {
            const float* pp = part + ((size_t)sp * N_NODES + m0 + lrow) * DOUT + (ksx - 256) + lk8;
            f32x4 v0 = *reinterpret_cast<const f32x4*>(pp);
            f32x4 v1 = *reinterpret_cast<const f32x4*>(pp + 4);
#pragma unroll
            for (int j = 0; j < 4; ++j) { s0[j] += v0[j]; s1[j] += v1[j]; }
        }
        bf16x8 a;
#pragma unroll
        for (int j = 0; j < 4; ++j) { a[j] = (bf16)(s0[j] * inv); a[4 + j] = (bf16)(s1[j] * inv); }
#pragma unroll
        for (int nb = 0; nb < 8; ++nb) {
            int col = wid * 128 + nb * 16 + lrow;
            bf16x8 b = *reinterpret_cast<const bf16x8*>(WfcT + (size_t)col * KCAT + ksx + lk8);
            acc[nb] = mfma16(a, b, acc[nb]);
        }
    }

    float ss = 0.f;
#pragma unroll
    for (int nb = 0; nb < 8; ++nb) {
        int col = wid * 128 + nb * 16 + lrow;
        float bias = bfc[col];
#pragma unroll
        for (int j = 0; j < 4; ++j) {
            int row = m0 + (lane >> 4) * 4 + j;
            float v = acc[nb][j] + bias;
            v = (v > 0.f ? v : 0.f) + EPSF;
            out[(size_t)row * DOUT + col] = v;
            ss += v * v;
        }
    }
#pragma unroll
    for (int off = 32; off; off >>= 1) ss += __shfl_xor(ss, off);
    __shared__ float sw[2];
    if (lane == 0) sw[wid] = ss;
    __syncthreads();
    if (threadIdx.x == 0) partials[blockIdx.x] = sw[0] + sw[1];
}

// ---------------- K4: deterministic reduce of 512 partials; scale out by 1/(norm+eps)
__global__ __launch_bounds__(256) void k4_norm(float* __restrict__ out,
                                               const float* __restrict__ partials) {
    __shared__ float sw[4];
    float s = partials[threadIdx.x] + partials[threadIdx.x + 256];
#pragma unroll
    for (int off = 32; off; off >>= 1) s += __shfl_xor(s, off);
    if ((threadIdx.x & 63) == 0) sw[threadIdx.x >> 6] = s;
    __syncthreads();
    float total = sw[0] + sw[1] + sw[2] + sw[3];
    float scale = 1.f / (sqrtf(total) + EPSF);
    f32x4* o4 = reinterpret_cast<f32x4*>(out);
    const int nvec = N_NODES * DOUT / 4;
    for (int i = blockIdx.x * blockDim.x + threadIdx.x; i < nvec; i += gridDim.x * blockDim.x) {
        f32x4 v = o4[i];
#pragma unroll
        for (int j = 0; j < 4; ++j) v[j] *= scale;
        o4[i] = v;
    }
}

extern "C" void kernel_launch(void* const* d_in, const int* in_sizes, int n_in,
                              void* d_out, int out_size, void* d_ws, size_t ws_size,
                              hipStream_t stream) {
    const float* A   = (const float*)d_in[0];
    const float* X   = (const float*)d_in[1];
    const float* Ww  = (const float*)d_in[2];
    const float* bw  = (const float*)d_in[3];
    const float* Wfc = (const float*)d_in[4];
    const float* bfc = (const float*)d_in[5];
    float* out = (float*)d_out;

    char* ws = (char*)d_ws;
    bf16*  hT        = (bf16*)(ws);                                  // 4 MiB
    bf16*  WwT       = (bf16*)(ws + (8u << 20));                     // 128 KiB
    bf16*  WfcT      = (bf16*)(ws + (8u << 20) + (128u << 10));      // 256 KiB
    float* partials  = (float*)(ws + (8u << 20) + (384u << 10));     // 2 KiB
    float* rsG       = (float*)(ws + (8u << 20) + (512u << 10));     // 128 KiB
    float* part      = (float*)(ws + (16u << 20));                   // 32 MiB

    k0_prep<<<512, 256, 0, stream>>>(Ww, Wfc, WwT, WfcT);
    k1_h<<<512, 128, 0, stream>>>(X, WwT, bw, hT);
    k2_pool<<<256, 512, 0, stream>>>(A, hT, part, rsG);
    k3_out<<<512, 128, 0, stream>>>(X, part, rsG, WfcT, bfc, out, partials);
    k4_norm<<<256, 256, 0, stream>>>(out, partials);
}

// Round 6
// 138.361 us; speedup vs baseline: 1.2210x; 1.2210x over previous
//
#include <hip/hip_runtime.h>
#include <hip/hip_bf16.h>
#include <math.h>

typedef __bf16 bf16;
typedef bf16 bf16x8 __attribute__((ext_vector_type(8)));
typedef bf16 bf16x4 __attribute__((ext_vector_type(4)));
typedef float f32x4 __attribute__((ext_vector_type(4)));

#define N_NODES 8192
#define DIN 256
#define DOUT 256
#define KCAT 512
#define EPSF 1e-8f
#define KSPLIT 4
#define KBLK 2048          // K per k2 block
#define BM 128
#define BK 64
#define NT (KBLK / BK)     // 32 tiles
#define BUFSZ 49152        // A 16 KB + B 32 KB

__device__ __forceinline__ f32x4 mfma16(bf16x8 a, bf16x8 b, f32x4 c) {
    return __builtin_amdgcn_mfma_f32_16x16x32_bf16(a, b, c, 0, 0, 0);
}

#define WAITVM(N) asm volatile("s_waitcnt vmcnt(" #N ")" ::: "memory")
#define WAITLGKM  asm volatile("s_waitcnt lgkmcnt(0)" ::: "memory")
#define BAR       __builtin_amdgcn_s_barrier()

// ---------------- K0: W_w [256x256] -> WwT[n][k] bf16 ; W_fc [512x256] -> WfcT[n][k] bf16
__global__ __launch_bounds__(256) void k0_prep(const float* __restrict__ Ww,
                                               const float* __restrict__ Wfc,
                                               bf16* __restrict__ WwT,
                                               bf16* __restrict__ WfcT) {
    int tid = blockIdx.x * 256 + threadIdx.x;
    if (tid < 256 * 256) {
        int n = tid >> 8, k = tid & 255;
        WwT[n * 256 + k] = (bf16)Ww[k * 256 + n];
    }
    if (tid < 256 * 512) {
        int n = tid >> 9, k = tid & 511;
        WfcT[n * 512 + k] = (bf16)Wfc[k * 256 + n];
    }
}

// ---------------- K1: hT[col][m] = bf16(relu(X @ W_w + b_w))
__global__ __launch_bounds__(128) void k1_h(const float* __restrict__ X,
                                            const bf16* __restrict__ WwT,
                                            const float* __restrict__ bw,
                                            bf16* __restrict__ hT) {
    const int lane = threadIdx.x & 63;
    const int wid  = threadIdx.x >> 6;   // 0..1
    const int m0   = blockIdx.x * 16;
    const int lrow = lane & 15;
    const int lk8  = (lane >> 4) * 8;

    f32x4 acc[8];
#pragma unroll
    for (int i = 0; i < 8; ++i) acc[i] = {0.f, 0.f, 0.f, 0.f};

#pragma unroll
    for (int ks = 0; ks < DIN; ks += 32) {
        const float* xp = X + (size_t)(m0 + lrow) * DIN + ks + lk8;
        f32x4 x0 = *reinterpret_cast<const f32x4*>(xp);
        f32x4 x1 = *reinterpret_cast<const f32x4*>(xp + 4);
        bf16x8 a;
#pragma unroll
        for (int j = 0; j < 4; ++j) { a[j] = (bf16)x0[j]; a[4 + j] = (bf16)x1[j]; }
#pragma unroll
        for (int nb = 0; nb < 8; ++nb) {
            int col = wid * 128 + nb * 16 + lrow;
            bf16x8 b = *reinterpret_cast<const bf16x8*>(WwT + (size_t)col * DIN + ks + lk8);
            acc[nb] = mfma16(a, b, acc[nb]);
        }
    }
    const int mrow = m0 + (lane >> 4) * 4;
#pragma unroll
    for (int nb = 0; nb < 8; ++nb) {
        int col = wid * 128 + nb * 16 + lrow;
        float bias = bw[col];
        bf16x4 hv;
#pragma unroll
        for (int j = 0; j < 4; ++j) {
            float v = acc[nb][j] + bias;
            hv[j] = (bf16)(v > 0.f ? v : 0.f);
        }
        *reinterpret_cast<bf16x4*>(hT + (size_t)col * N_NODES + mrow) = hv;
    }
}

// ---------------- K2: partial pooled = A[m0:m0+128, kbase:kbase+2048] @ h[k-range]
// EXACT round-3 structure (BK=64, 2-stage, counted vmcnt) + ONE change:
// circular K-loop with per-block start phase ((5*mblk + 8*ks) & 31) so the
// A-stream k-offsets decorrelate across blocks (break HBM/L3 channel camping
// from the global 32KB-stride phase lock).
__global__ __launch_bounds__(512) void k2_pool(const float* __restrict__ A,
                                               const bf16* __restrict__ hT,
                                               float* __restrict__ part,
                                               float* __restrict__ rsG) {
    __shared__ __align__(16) unsigned char lds[2][BUFSZ];
    __shared__ float rsp[2][BM];
    const int t    = threadIdx.x;
    const int lane = t & 63;
    const int wid  = t >> 6;        // 0..7
    const int wr   = wid >> 2;      // 0..1  (row half)
    const int wn   = wid & 3;       // 0..3  (col quarter)
    const int lrow = lane & 15;
    const int lk4  = lane >> 4;     // 0..3
    const int mblk = blockIdx.x & 63;
    const int ks   = blockIdx.x >> 6;
    const int m0   = mblk * BM;
    const int kbase = ks * KBLK;
    const int start = (5 * mblk + 8 * ks) & (NT - 1);

#define PHYS(tl) (((tl) + start) & (NT - 1))

    f32x4 acc[4][4];
    f32x4 sums[4];
#pragma unroll
    for (int i = 0; i < 4; ++i) {
        sums[i] = {0.f, 0.f, 0.f, 0.f};
#pragma unroll
        for (int j = 0; j < 4; ++j) acc[i][j] = {0.f, 0.f, 0.f, 0.f};
    }
    bf16x8 bOne;
#pragma unroll
    for (int j = 0; j < 8; ++j) bOne[j] = (bf16)1.0f;

    // ---- A staging assignment: thread t -> row t>>2, 16 floats at (t&3)*16
    const int arow = t >> 2;
    const int aq   = t & 3;
    const float* aSrc = A + (size_t)(m0 + arow) * N_NODES + kbase + aq * 16;
    const int awb0 = arow * 128 + (((aq * 2)     ^ (arow & 7)) << 4);
    const int awb1 = arow * 128 + (((aq * 2 + 1) ^ (arow & 7)) << 4);

    // ---- B DMA assignment (4 rounds): idx = r*512+t -> col=idx>>3, seg=(idx&7)^(col&7)
    int bcol[4], bseg[4], bldsoff[4];
#pragma unroll
    for (int r = 0; r < 4; ++r) {
        int idx = r * 512 + t;
        bcol[r] = idx >> 3;
        bseg[r] = (idx & 7) ^ (bcol[r] & 7);
        bldsoff[r] = 16384 + (r * 8 + wid) * 1024;   // wave-uniform base within buffer
    }

    // ---- fragment read byte offsets
    int aOff[2][4], bOff[2][4];
#pragma unroll
    for (int kki = 0; kki < 2; ++kki) {
        int sA = kki * 4 + lk4;
#pragma unroll
        for (int f = 0; f < 4; ++f) {
            int row = wr * 64 + f * 16 + lrow;
            aOff[kki][f] = row * 128 + ((sA ^ (row & 7)) << 4);
            int col = wn * 64 + f * 16 + lrow;
            bOff[kki][f] = 16384 + col * 128 + ((sA ^ (col & 7)) << 4);
        }
    }

    f32x4 ra0, ra1, ra2, ra3;

#define ALOAD(tile) do {                                                      \
        const float* p_ = aSrc + (size_t)PHYS(tile) * BK;                     \
        ra0 = *reinterpret_cast<const f32x4*>(p_);                            \
        ra1 = *reinterpret_cast<const f32x4*>(p_ + 4);                        \
        ra2 = *reinterpret_cast<const f32x4*>(p_ + 8);                        \
        ra3 = *reinterpret_cast<const f32x4*>(p_ + 12);                       \
    } while (0)

#define CVTWRITE(bufidx) do {                                                 \
        bf16x8 w0_, w1_;                                                      \
        _Pragma("unroll")                                                     \
        for (int j = 0; j < 4; ++j) {                                         \
            w0_[j] = (bf16)ra0[j]; w0_[4 + j] = (bf16)ra1[j];                 \
            w1_[j] = (bf16)ra2[j]; w1_[4 + j] = (bf16)ra3[j];                 \
        }                                                                     \
        *reinterpret_cast<bf16x8*>(&lds[bufidx][awb0]) = w0_;                 \
        *reinterpret_cast<bf16x8*>(&lds[bufidx][awb1]) = w1_;                 \
    } while (0)

#define BDMA(tile, bufidx) do {                                               \
        _Pragma("unroll")                                                     \
        for (int r_ = 0; r_ < 4; ++r_) {                                      \
            const bf16* g_ = hT + (size_t)bcol[r_] * N_NODES + kbase          \
                             + (size_t)PHYS(tile) * BK + bseg[r_] * 8;        \
            __builtin_amdgcn_global_load_lds(                                 \
                (const __attribute__((address_space(1))) void*)g_,            \
                (__attribute__((address_space(3))) void*)&lds[bufidx][bldsoff[r_]], \
                16, 0, 0);                                                    \
        }                                                                     \
    } while (0)

#define COMPUTE(bufidx) do {                                                  \
        _Pragma("unroll")                                                     \
        for (int kki = 0; kki < 2; ++kki) {                                   \
            bf16x8 af_[4], bf_[4];                                            \
            _Pragma("unroll")                                                 \
            for (int f = 0; f < 4; ++f) {                                     \
                af_[f] = *reinterpret_cast<const bf16x8*>(&lds[bufidx][aOff[kki][f]]); \
                bf_[f] = *reinterpret_cast<const bf16x8*>(&lds[bufidx][bOff[kki][f]]); \
            }                                                                 \
            _Pragma("unroll")                                                 \
            for (int mf = 0; mf < 4; ++mf)                                    \
                _Pragma("unroll")                                             \
                for (int nf = 0; nf < 4; ++nf)                                \
                    acc[mf][nf] = mfma16(af_[mf], bf_[nf], acc[mf][nf]);      \
            if (wn == kki) {                                                  \
                _Pragma("unroll")                                             \
                for (int mf = 0; mf < 4; ++mf)                                \
                    sums[mf] = mfma16(af_[mf], bOne, sums[mf]);               \
            }                                                                 \
        }                                                                     \
    } while (0)

    // ---------------- prologue
    ALOAD(0); BDMA(0, 0);
    CVTWRITE(0);                 // compiler inserts precise vmcnt for ra use
    ALOAD(1); BDMA(1, 1);
    WAITVM(8);                   // B(0) done; A(1)+B(1) (8 newest) may remain
    WAITLGKM;
    BAR;                         // tile 0 ready for all waves

    // ---------------- main loop: tiles 0 .. NT-3
    for (int tt = 0; tt < NT - 2; ++tt) {
        CVTWRITE((tt + 1) & 1);  // A(tt+1) regs -> LDS (compiler waits vmcnt(4))
        COMPUTE(tt & 1);
        ALOAD(tt + 2);
        WAITVM(4);               // B(tt+1) done; A(tt+2) (4 newest) in flight
        WAITLGKM;
        BAR;                     // tile tt+1 ready; all waves done reading buf[tt&1]
        BDMA(tt + 2, tt & 1);
    }
    // ---------------- tail: tiles NT-2, NT-1
    CVTWRITE((NT - 1) & 1);
    COMPUTE((NT - 2) & 1);
    WAITVM(0);                   // drain B(NT-1)
    WAITLGKM;
    BAR;
    COMPUTE((NT - 1) & 1);

    // ---------------- rowsum reduce (waves wn==0/1 hold kki 0/1 partials)
    if (wn < 2 && lrow == 0) {
#pragma unroll
        for (int mf = 0; mf < 4; ++mf)
#pragma unroll
            for (int j = 0; j < 4; ++j)
                rsp[wn][wr * 64 + mf * 16 + lk4 * 4 + j] = sums[mf][j];
    }
    __syncthreads();
    if (t < BM) rsG[(size_t)ks * N_NODES + m0 + t] = rsp[0][t] + rsp[1][t];

    // ---------------- store f32 partial tile
    float* pp = part + ((size_t)ks * N_NODES + m0) * DOUT;
#pragma unroll
    for (int mf = 0; mf < 4; ++mf)
#pragma unroll
        for (int nf = 0; nf < 4; ++nf) {
            int col = wn * 64 + nf * 16 + lrow;
#pragma unroll
            for (int j = 0; j < 4; ++j) {
                int row = wr * 64 + mf * 16 + lk4 * 4 + j;
                pp[(size_t)row * DOUT + col] = acc[mf][nf][j];
            }
        }
#undef ALOAD
#undef CVTWRITE
#undef BDMA
#undef COMPUTE
#undef PHYS
}

// ---------------- K3: out = relu([X || pooled] @ W_fc + b_fc) + eps  (pooled formed
// on the fly from part/rsG — k2b merged in), + per-block sumsq partial
__global__ __launch_bounds__(128) void k3_out(const float* __restrict__ X,
                                              const float* __restrict__ part,
                                              const float* __restrict__ rsG,
                                              const bf16* __restrict__ WfcT,
                                              const float* __restrict__ bfc,
                                              float* __restrict__ out,
                                              float* __restrict__ partials) {
    const int lane = threadIdx.x & 63;
    const int wid  = threadIdx.x >> 6;
    const int m0   = blockIdx.x * 16;
    const int lrow = lane & 15;
    const int lk8  = (lane >> 4) * 8;

    f32x4 acc[8];
#pragma unroll
    for (int i = 0; i < 8; ++i) acc[i] = {0.f, 0.f, 0.f, 0.f};

    // per-lane row scale 1/(rowsum+eps) for row m0+lrow
    float rs = EPSF;
#pragma unroll
    for (int sp = 0; sp < KSPLIT; ++sp) rs += rsG[(size_t)sp * N_NODES + m0 + lrow];
    const float inv = 1.f / rs;

    // k in [0,256): A-operand from X (fp32 -> bf16)
#pragma unroll
    for (int ksx = 0; ksx < 256; ksx += 32) {
        const float* xp = X + (size_t)(m0 + lrow) * DIN + ksx + lk8;
        f32x4 x0 = *reinterpret_cast<const f32x4*>(xp);
        f32x4 x1 = *reinterpret_cast<const f32x4*>(xp + 4);
        bf16x8 a;
#pragma unroll
        for (int j = 0; j < 4; ++j) { a[j] = (bf16)x0[j]; a[4 + j] = (bf16)x1[j]; }
#pragma unroll
        for (int nb = 0; nb < 8; ++nb) {
            int col = wid * 128 + nb * 16 + lrow;
            bf16x8 b = *reinterpret_cast<const bf16x8*>(WfcT + (size_t)col * KCAT + ksx + lk8);
            acc[nb] = mfma16(a, b, acc[nb]);
        }
    }
    // k in [256,512): A-operand = pooled, formed from sum of part splits * inv
#pragma unroll
    for (int ksx = 256; ksx < 512; ksx += 32) {
        f32x4 s0 = {0.f, 0.f, 0.f, 0.f}, s1 = {0.f, 0.f, 0.f, 0.f};
#pragma unroll
        for (int sp = 0; sp < KSPLIT; ++sp) {
            const float* pp = part + ((size_t)sp * N_NODES + m0 + lrow) * DOUT + (ksx - 256) + lk8;
            f32x4 v0 = *reinterpret_cast<const f32x4*>(pp);
            f32x4 v1 = *reinterpret_cast<const f32x4*>(pp + 4);
#pragma unroll
            for (int j = 0; j < 4; ++j) { s0[j] += v0[j]; s1[j] += v1[j]; }
        }
        bf16x8 a;
#pragma unroll
        for (int j = 0; j < 4; ++j) { a[j] = (bf16)(s0[j] * inv); a[4 + j] = (bf16)(s1[j] * inv); }
#pragma unroll
        for (int nb = 0; nb < 8; ++nb) {
            int col = wid * 128 + nb * 16 + lrow;
            bf16x8 b = *reinterpret_cast<const bf16x8*>(WfcT + (size_t)col * KCAT + ksx + lk8);
            acc[nb] = mfma16(a, b, acc[nb]);
        }
    }

    float ss = 0.f;
#pragma unroll
    for (int nb = 0; nb < 8; ++nb) {
        int col = wid * 128 + nb * 16 + lrow;
        float bias = bfc[col];
#pragma unroll
        for (int j = 0; j < 4; ++j) {
            int row = m0 + (lane >> 4) * 4 + j;
            float v = acc[nb][j] + bias;
            v = (v > 0.f ? v : 0.f) + EPSF;
            out[(size_t)row * DOUT + col] = v;
            ss += v * v;
        }
    }
#pragma unroll
    for (int off = 32; off; off >>= 1) ss += __shfl_xor(ss, off);
    __shared__ float sw[2];
    if (lane == 0) sw[wid] = ss;
    __syncthreads();
    if (threadIdx.x == 0) partials[blockIdx.x] = sw[0] + sw[1];
}

// ---------------- K4: deterministic reduce of 512 partials; scale out by 1/(norm+eps)
__global__ __launch_bounds__(256) void k4_norm(float* __restrict__ out,
                                               const float* __restrict__ partials) {
    __shared__ float sw[4];
    float s = partials[threadIdx.x] + partials[threadIdx.x + 256];
#pragma unroll
    for (int off = 32; off; off >>= 1) s += __shfl_xor(s, off);
    if ((threadIdx.x & 63) == 0) sw[threadIdx.x >> 6] = s;
    __syncthreads();
    float total = sw[0] + sw[1] + sw[2] + sw[3];
    float scale = 1.f / (sqrtf(total) + EPSF);
    f32x4* o4 = reinterpret_cast<f32x4*>(out);
    const int nvec = N_NODES * DOUT / 4;
    for (int i = blockIdx.x * blockDim.x + threadIdx.x; i < nvec; i += gridDim.x * blockDim.x) {
        f32x4 v = o4[i];
#pragma unroll
        for (int j = 0; j < 4; ++j) v[j] *= scale;
        o4[i] = v;
    }
}

extern "C" void kernel_launch(void* const* d_in, const int* in_sizes, int n_in,
                              void* d_out, int out_size, void* d_ws, size_t ws_size,
                              hipStream_t stream) {
    const float* A   = (const float*)d_in[0];
    const float* X   = (const float*)d_in[1];
    const float* Ww  = (const float*)d_in[2];
    const float* bw  = (const float*)d_in[3];
    const float* Wfc = (const float*)d_in[4];
    const float* bfc = (const float*)d_in[5];
    float* out = (float*)d_out;

    char* ws = (char*)d_ws;
    bf16*  hT        = (bf16*)(ws);                                  // 4 MiB
    bf16*  WwT       = (bf16*)(ws + (8u << 20));                     // 128 KiB
    bf16*  WfcT     = (bf16*)(ws + (8u << 20) + (128u << 10));       // 256 KiB
    float* partials  = (float*)(ws + (8u << 20) + (384u << 10));     // 2 KiB
    float* rsG       = (float*)(ws + (8u << 20) + (512u << 10));     // 128 KiB
    float* part      = (float*)(ws + (16u << 20));                   // 32 MiB

    k0_prep<<<512, 256, 0, stream>>>(Ww, Wfc, WwT, WfcT);
    k1_h<<<512, 128, 0, stream>>>(X, WwT, bw, hT);
    k2_pool<<<256, 512, 0, stream>>>(A, hT, part, rsG);
    k3_out<<<512, 128, 0, stream>>>(X, part, rsG, WfcT, bfc, out, partials);
    k4_norm<<<256, 256, 0, stream>>>(out, partials);
}

// Round 7
// 136.933 us; speedup vs baseline: 1.2337x; 1.0104x over previous
//
#include <hip/hip_runtime.h>
#include <hip/hip_bf16.h>
#include <math.h>

typedef __bf16 bf16;
typedef bf16 bf16x8 __attribute__((ext_vector_type(8)));
typedef bf16 bf16x4 __attribute__((ext_vector_type(4)));
typedef float f32x4 __attribute__((ext_vector_type(4)));

#define N_NODES 8192
#define DIN 256
#define DOUT 256
#define KCAT 512
#define EPSF 1e-8f
#define KSPLIT 4
#define KBLK 2048          // K per k2 block
#define BM 128
#define BK 64
#define NT (KBLK / BK)     // 32 tiles = 8 groups of 4
#define BUFSZ 49152        // A 16 KB + B 32 KB

__device__ __forceinline__ f32x4 mfma16(bf16x8 a, bf16x8 b, f32x4 c) {
    return __builtin_amdgcn_mfma_f32_16x16x32_bf16(a, b, c, 0, 0, 0);
}

#define WAITVM(N) asm volatile("s_waitcnt vmcnt(" #N ")" ::: "memory")
#define WAITLGKM  asm volatile("s_waitcnt lgkmcnt(0)" ::: "memory")
#define BAR       __builtin_amdgcn_s_barrier()
#define SBAR      __builtin_amdgcn_sched_barrier(0)

// ---------------- K0: W_w [256x256] -> WwT[n][k] bf16 ; W_fc [512x256] -> WfcT[n][k] bf16
__global__ __launch_bounds__(256) void k0_prep(const float* __restrict__ Ww,
                                               const float* __restrict__ Wfc,
                                               bf16* __restrict__ WwT,
                                               bf16* __restrict__ WfcT) {
    int tid = blockIdx.x * 256 + threadIdx.x;
    if (tid < 256 * 256) {
        int n = tid >> 8, k = tid & 255;
        WwT[n * 256 + k] = (bf16)Ww[k * 256 + n];
    }
    if (tid < 256 * 512) {
        int n = tid >> 9, k = tid & 511;
        WfcT[n * 512 + k] = (bf16)Wfc[k * 256 + n];
    }
}

// ---------------- K1: hT[col][m] = bf16(relu(X @ W_w + b_w))
__global__ __launch_bounds__(128) void k1_h(const float* __restrict__ X,
                                            const bf16* __restrict__ WwT,
                                            const float* __restrict__ bw,
                                            bf16* __restrict__ hT) {
    const int lane = threadIdx.x & 63;
    const int wid  = threadIdx.x >> 6;   // 0..1
    const int m0   = blockIdx.x * 16;
    const int lrow = lane & 15;
    const int lk8  = (lane >> 4) * 8;

    f32x4 acc[8];
#pragma unroll
    for (int i = 0; i < 8; ++i) acc[i] = {0.f, 0.f, 0.f, 0.f};

#pragma unroll
    for (int ks = 0; ks < DIN; ks += 32) {
        const float* xp = X + (size_t)(m0 + lrow) * DIN + ks + lk8;
        f32x4 x0 = *reinterpret_cast<const f32x4*>(xp);
        f32x4 x1 = *reinterpret_cast<const f32x4*>(xp + 4);
        bf16x8 a;
#pragma unroll
        for (int j = 0; j < 4; ++j) { a[j] = (bf16)x0[j]; a[4 + j] = (bf16)x1[j]; }
#pragma unroll
        for (int nb = 0; nb < 8; ++nb) {
            int col = wid * 128 + nb * 16 + lrow;
            bf16x8 b = *reinterpret_cast<const bf16x8*>(WwT + (size_t)col * DIN + ks + lk8);
            acc[nb] = mfma16(a, b, acc[nb]);
        }
    }
    const int mrow = m0 + (lane >> 4) * 4;
#pragma unroll
    for (int nb = 0; nb < 8; ++nb) {
        int col = wid * 128 + nb * 16 + lrow;
        float bias = bw[col];
        bf16x4 hv;
#pragma unroll
        for (int j = 0; j < 4; ++j) {
            float v = acc[nb][j] + bias;
            hv[j] = (bf16)(v > 0.f ? v : 0.f);
        }
        *reinterpret_cast<bf16x4*>(hT + (size_t)col * N_NODES + mrow) = hv;
    }
}

// ---------------- K2: part[ks] = A[m0:m0+128, kbase:+2048] @ h ; rsG[ks] = rowsum partial
// R3 structure (BK=64, 2-stage dbuf, counted vmcnt) + grouped A-fetch:
// A loaded 4 tiles (256 cols) at a time -> 1 KB contiguous DRAM burst per row
// (vs 256 B before) to fix DRAM page-activation efficiency (the invariant
// across R3-R6's ~2.4 TB/s A-stream wall). Two 64-VGPR A-reg sets ping-pong
// by group parity; all indices compile-time (full unroll, 8 groups).
// Rowsum: fp32 VALU adds on A-regs during cvt + shfl_xor reduce (no MFMA).
// vmcnt ladder (hand-traced): s=0:0, s=1:16, s=2:0, s=3:0; all retires >=1 iter mature.
__global__ __launch_bounds__(512, 2) void k2_pool(const float* __restrict__ A,
                                                  const bf16* __restrict__ hT,
                                                  float* __restrict__ part,
                                                  float* __restrict__ rsG) {
    __shared__ __align__(16) unsigned char lds[2][BUFSZ];
    const int t    = threadIdx.x;
    const int lane = t & 63;
    const int wid  = t >> 6;        // 0..7
    const int wr   = wid >> 2;      // 0..1  (row half)
    const int wn   = wid & 3;       // 0..3  (col quarter)
    const int lrow = lane & 15;
    const int lk4  = lane >> 4;     // 0..3
    const int mblk = blockIdx.x & 63;
    const int ks   = blockIdx.x >> 6;
    const int m0   = mblk * BM;
    const int kbase = ks * KBLK;

    f32x4 acc[4][4];
#pragma unroll
    for (int i = 0; i < 4; ++i)
#pragma unroll
        for (int j = 0; j < 4; ++j) acc[i][j] = {0.f, 0.f, 0.f, 0.f};

    float rsum = 0.f;

    // ---- A staging: thread t -> row t>>2, col-quarter t&3 (16 floats/tile)
    const int arow = t >> 2;
    const int aq   = t & 3;
    const float* aSrc = A + (size_t)(m0 + arow) * N_NODES + kbase + aq * 16;
    const int awb0 = arow * 128 + (((aq * 2)     ^ (arow & 7)) << 4);
    const int awb1 = arow * 128 + (((aq * 2 + 1) ^ (arow & 7)) << 4);

    // ---- B DMA assignment (4 rounds): idx = r*512+t -> col=idx>>3, seg=(idx&7)^(col&7)
    int bcol[4], bseg[4], bldsoff[4];
#pragma unroll
    for (int r = 0; r < 4; ++r) {
        int idx = r * 512 + t;
        bcol[r] = idx >> 3;
        bseg[r] = (idx & 7) ^ (bcol[r] & 7);
        bldsoff[r] = 16384 + (r * 8 + wid) * 1024;   // wave-uniform base within buffer
    }

    // ---- fragment read byte offsets
    int aOff[2][4], bOff[2][4];
#pragma unroll
    for (int kki = 0; kki < 2; ++kki) {
        int sA = kki * 4 + lk4;
#pragma unroll
        for (int f = 0; f < 4; ++f) {
            int row = wr * 64 + f * 16 + lrow;
            aOff[kki][f] = row * 128 + ((sA ^ (row & 7)) << 4);
            int col = wn * 64 + f * 16 + lrow;
            bOff[kki][f] = 16384 + col * 128 + ((sA ^ (col & 7)) << 4);
        }
    }

    f32x4 S0[4][4], S1[4][4];   // two A-reg group sets (4 sub-tiles x 4 f32x4)

#define ALOAD16(SET, g) do {                                                  \
        _Pragma("unroll")                                                     \
        for (int s_ = 0; s_ < 4; ++s_)                                        \
            _Pragma("unroll")                                                 \
            for (int q_ = 0; q_ < 4; ++q_)                                    \
                SET[s_][q_] = *reinterpret_cast<const f32x4*>(                \
                    aSrc + (size_t)(g) * 256 + s_ * 64 + q_ * 4);             \
    } while (0)

#define CVTW(SET, sub, bufidx) do {                                           \
        bf16x8 w0_, w1_;                                                      \
        _Pragma("unroll")                                                     \
        for (int j_ = 0; j_ < 4; ++j_) {                                      \
            w0_[j_]     = (bf16)SET[sub][0][j_];                              \
            w0_[4 + j_] = (bf16)SET[sub][1][j_];                              \
            w1_[j_]     = (bf16)SET[sub][2][j_];                              \
            w1_[4 + j_] = (bf16)SET[sub][3][j_];                              \
            rsum += SET[sub][0][j_] + SET[sub][1][j_]                         \
                  + SET[sub][2][j_] + SET[sub][3][j_];                        \
        }                                                                     \
        *reinterpret_cast<bf16x8*>(&lds[bufidx][awb0]) = w0_;                 \
        *reinterpret_cast<bf16x8*>(&lds[bufidx][awb1]) = w1_;                 \
    } while (0)

#define BDMA(tile, bufidx) do {                                               \
        _Pragma("unroll")                                                     \
        for (int r_ = 0; r_ < 4; ++r_) {                                      \
            const bf16* g_ = hT + (size_t)bcol[r_] * N_NODES + kbase          \
                             + (size_t)(tile) * BK + bseg[r_] * 8;            \
            __builtin_amdgcn_global_load_lds(                                 \
                (const __attribute__((address_space(1))) void*)g_,            \
                (__attribute__((address_space(3))) void*)&lds[bufidx][bldsoff[r_]], \
                16, 0, 0);                                                    \
        }                                                                     \
    } while (0)

#define COMPUTE(bufidx) do {                                                  \
        _Pragma("unroll")                                                     \
        for (int kki = 0; kki < 2; ++kki) {                                   \
            bf16x8 af_[4], bf_[4];                                            \
            _Pragma("unroll")                                                 \
            for (int f = 0; f < 4; ++f) {                                     \
                af_[f] = *reinterpret_cast<const bf16x8*>(&lds[bufidx][aOff[kki][f]]); \
                bf_[f] = *reinterpret_cast<const bf16x8*>(&lds[bufidx][bOff[kki][f]]); \
            }                                                                 \
            _Pragma("unroll")                                                 \
            for (int mf = 0; mf < 4; ++mf)                                    \
                _Pragma("unroll")                                             \
                for (int nf = 0; nf < 4; ++nf)                                \
                    acc[mf][nf] = mfma16(af_[mf], bf_[nf], acc[mf][nf]);      \
        }                                                                     \
    } while (0)

// one group body: tiles 4g..4g+3 computed; CVTs tiles 4g+1..4g+4; B DMA 4g+2..4g+5;
// A-group g+1 (16 loads, 1 KB/row burst) issued after s=0's BDMA.
#define BODY(g, SC, SN) do {                                                  \
        CVTW(SC, 1, 1); COMPUTE(0);                                           \
        WAITVM(0); WAITLGKM; BAR;                                             \
        BDMA(4*(g)+2, 0); SBAR; ALOAD16(SN, (g)+1); SBAR;                     \
        CVTW(SC, 2, 0); COMPUTE(1);                                           \
        WAITVM(16); WAITLGKM; BAR;                                            \
        BDMA(4*(g)+3, 1);                                                     \
        CVTW(SC, 3, 1); COMPUTE(0);                                           \
        WAITVM(0); WAITLGKM; BAR;                                             \
        BDMA(4*(g)+4, 0);                                                     \
        CVTW(SN, 0, 0); COMPUTE(1);                                           \
        WAITVM(0); WAITLGKM; BAR;                                             \
        BDMA(4*(g)+5, 1);                                                     \
    } while (0)

    // ---------------- prologue: group 0 A, tiles 0/1 B, tile 0 staged
    ALOAD16(S0, 0); SBAR;
    BDMA(0, 0);
    CVTW(S0, 0, 0);              // compiler waits precisely on S0[0][*]
    BDMA(1, 1);
    WAITVM(4);                   // retire A16(0)+B(0); leave B(1) in flight
    WAITLGKM;
    BAR;                         // tile 0 ready

    // ---------------- 7 steady groups (fully unrolled, static set parity)
    BODY(0, S0, S1);
    BODY(1, S1, S0);
    BODY(2, S0, S1);
    BODY(3, S1, S0);
    BODY(4, S0, S1);
    BODY(5, S1, S0);
    BODY(6, S0, S1);
    // ---------------- tail group 7 (tiles 28..31, data in S1)
    CVTW(S1, 1, 1); COMPUTE(0);
    WAITVM(0); WAITLGKM; BAR;
    BDMA(30, 0);
    CVTW(S1, 2, 0); COMPUTE(1);
    WAITVM(0); WAITLGKM; BAR;
    BDMA(31, 1);
    CVTW(S1, 3, 1); COMPUTE(0);
    WAITVM(0); WAITLGKM; BAR;
    COMPUTE(1);

    // ---------------- rowsum: reduce the 4 col-quarter partials per row
    rsum += __shfl_xor(rsum, 1);
    rsum += __shfl_xor(rsum, 2);
    if ((t & 3) == 0) rsG[(size_t)ks * N_NODES + m0 + arow] = rsum;

    // ---------------- store f32 partial tile
    float* pp = part + ((size_t)ks * N_NODES + m0) * DOUT;
#pragma unroll
    for (int mf = 0; mf < 4; ++mf)
#pragma unroll
        for (int nf = 0; nf < 4; ++nf) {
            int col = wn * 64 + nf * 16 + lrow;
#pragma unroll
            for (int j = 0; j < 4; ++j) {
                int row = wr * 64 + mf * 16 + lk4 * 4 + j;
                pp[(size_t)row * DOUT + col] = acc[mf][nf][j];
            }
        }
#undef ALOAD16
#undef CVTW
#undef BDMA
#undef COMPUTE
#undef BODY
}

// ---------------- K3: out = relu([X || pooled] @ W_fc + b_fc) + eps  (pooled formed
// on the fly from part/rsG — k2b merged in), + per-block sumsq partial
__global__ __launch_bounds__(128) void k3_out(const float* __restrict__ X,
                                              const float* __restrict__ part,
                                              const float* __restrict__ rsG,
                                              const bf16* __restrict__ WfcT,
                                              const float* __restrict__ bfc,
                                              float* __restrict__ out,
                                              float* __restrict__ partials) {
    const int lane = threadIdx.x & 63;
    const int wid  = threadIdx.x >> 6;
    const int m0   = blockIdx.x * 16;
    const int lrow = lane & 15;
    const int lk8  = (lane >> 4) * 8;

    f32x4 acc[8];
#pragma unroll
    for (int i = 0; i < 8; ++i) acc[i] = {0.f, 0.f, 0.f, 0.f};

    // per-lane row scale 1/(rowsum+eps) for row m0+lrow
    float rs = EPSF;
#pragma unroll
    for (int sp = 0; sp < KSPLIT; ++sp) rs += rsG[(size_t)sp * N_NODES + m0 + lrow];
    const float inv = 1.f / rs;

    // k in [0,256): A-operand from X (fp32 -> bf16)
#pragma unroll
    for (int ksx = 0; ksx < 256; ksx += 32) {
        const float* xp = X + (size_t)(m0 + lrow) * DIN + ksx + lk8;
        f32x4 x0 = *reinterpret_cast<const f32x4*>(xp);
        f32x4 x1 = *reinterpret_cast<const f32x4*>(xp + 4);
        bf16x8 a;
#pragma unroll
        for (int j = 0; j < 4; ++j) { a[j] = (bf16)x0[j]; a[4 + j] = (bf16)x1[j]; }
#pragma unroll
        for (int nb = 0; nb < 8; ++nb) {
            int col = wid * 128 + nb * 16 + lrow;
            bf16x8 b = *reinterpret_cast<const bf16x8*>(WfcT + (size_t)col * KCAT + ksx + lk8);
            acc[nb] = mfma16(a, b, acc[nb]);
        }
    }
    // k in [256,512): A-operand = pooled, formed from sum of part splits * inv
#pragma unroll
    for (int ksx = 256; ksx < 512; ksx += 32) {
        f32x4 s0 = {0.f, 0.f, 0.f, 0.f}, s1 = {0.f, 0.f, 0.f, 0.f};
#pragma unroll
        for (int sp = 0; sp < KSPLIT; ++sp) {
            const float* pp = part + ((size_t)sp * N_NODES + m0 + lrow) * DOUT + (ksx - 256) + lk8;
            f32x4 v0 = *reinterpret_cast<const f32x4*>(pp);
            f32x4 v1 = *reinterpret_cast<const f32x4*>(pp + 4);
#pragma unroll
            for (int j = 0; j < 4; ++j) { s0[j] += v0[j]; s1[j] += v1[j]; }
        }
        bf16x8 a;
#pragma unroll
        for (int j = 0; j < 4; ++j) { a[j] = (bf16)(s0[j] * inv); a[4 + j] = (bf16)(s1[j] * inv); }
#pragma unroll
        for (int nb = 0; nb < 8; ++nb) {
            int col = wid * 128 + nb * 16 + lrow;
            bf16x8 b = *reinterpret_cast<const bf16x8*>(WfcT + (size_t)col * KCAT + ksx + lk8);
            acc[nb] = mfma16(a, b, acc[nb]);
        }
    }

    float ss = 0.f;
#pragma unroll
    for (int nb = 0; nb < 8; ++nb) {
        int col = wid * 128 + nb * 16 + lrow;
        float bias = bfc[col];
#pragma unroll
        for (int j = 0; j < 4; ++j) {
            int row = m0 + (lane >> 4) * 4 + j;
            float v = acc[nb][j] + bias;
            v = (v > 0.f ? v : 0.f) + EPSF;
            out[(size_t)row * DOUT + col] = v;
            ss += v * v;
        }
    }
#pragma unroll
    for (int off = 32; off; off >>= 1) ss += __shfl_xor(ss, off);
    __shared__ float sw[2];
    if (lane == 0) sw[wid] = ss;
    __syncthreads();
    if (threadIdx.x == 0) partials[blockIdx.x] = sw[0] + sw[1];
}

// ---------------- K4: deterministic reduce of 512 partials; scale out by 1/(norm+eps)
__global__ __launch_bounds__(256) void k4_norm(float* __restrict__ out,
                                               const float* __restrict__ partials) {
    __shared__ float sw[4];
    float s = partials[threadIdx.x] + partials[threadIdx.x + 256];
#pragma unroll
    for (int off = 32; off; off >>= 1) s += __shfl_xor(s, off);
    if ((threadIdx.x & 63) == 0) sw[threadIdx.x >> 6] = s;
    __syncthreads();
    float total = sw[0] + sw[1] + sw[2] + sw[3];
    float scale = 1.f / (sqrtf(total) + EPSF);
    f32x4* o4 = reinterpret_cast<f32x4*>(out);
    const int nvec = N_NODES * DOUT / 4;
    for (int i = blockIdx.x * blockDim.x + threadIdx.x; i < nvec; i += gridDim.x * blockDim.x) {
        f32x4 v = o4[i];
#pragma unroll
        for (int j = 0; j < 4; ++j) v[j] *= scale;
        o4[i] = v;
    }
}

extern "C" void kernel_launch(void* const* d_in, const int* in_sizes, int n_in,
                              void* d_out, int out_size, void* d_ws, size_t ws_size,
                              hipStream_t stream) {
    const float* A   = (const float*)d_in[0];
    const float* X   = (const float*)d_in[1];
    const float* Ww  = (const float*)d_in[2];
    const float* bw  = (const float*)d_in[3];
    const float* Wfc = (const float*)d_in[4];
    const float* bfc = (const float*)d_in[5];
    float* out = (float*)d_out;

    char* ws = (char*)d_ws;
    bf16*  hT        = (bf16*)(ws);                                  // 4 MiB
    bf16*  WwT       = (bf16*)(ws + (8u << 20));                     // 128 KiB
    bf16*  WfcT      = (bf16*)(ws + (8u << 20) + (128u << 10));      // 256 KiB
    float* partials  = (float*)(ws + (8u << 20) + (384u << 10));     // 2 KiB
    float* rsG       = (float*)(ws + (8u << 20) + (512u << 10));     // 128 KiB
    float* part      = (float*)(ws + (16u << 20));                   // 32 MiB

    k0_prep<<<512, 256, 0, stream>>>(Ww, Wfc, WwT, WfcT);
    k1_h<<<512, 128, 0, stream>>>(X, WwT, bw, hT);
    k2_pool<<<256, 512, 0, stream>>>(A, hT, part, rsG);
    k3_out<<<512, 128, 0, stream>>>(X, part, rsG, WfcT, bfc, out, partials);
    k4_norm<<<256, 256, 0, stream>>>(out, partials);
}